// Round 1
// baseline (619.577 us; speedup 1.0000x reference)
//
#include <hip/hip_runtime.h>
#include <hip/hip_bf16.h>
#include <stdint.h>

// DCLS2d: B=16, Cin=Cout=128, H=W=112, KH=KW=3, DIL=4, D=9, PAD=4
//
// Stage 1 (build_K): construct dense K (Cout,Cin,9,9) in bf16 from weight+P,
//   stored in GEMM-staging layout: elem(tap,o,c) at
//   ((tap*8 + c/16)*2 + (c/8)%2)*1024 + o*8 + (c%8)   [bf16], total 2.65 MB in d_ws.
// Stage 2 (dcls_conv): implicit conv as 81 tap-shifted GEMM accumulations,
//   MFMA 32x32x16_bf16, reduction over Cin in chunks of 16.
//   Block tile: all 128 Cout x (16x16 spatial). 784 blocks, no padding waste.

typedef __attribute__((ext_vector_type(8))) short short8;
typedef __attribute__((ext_vector_type(16))) float f32x16;

__device__ inline unsigned short f2bf(float f) {
    union { float f; unsigned int u; } v; v.f = f;
    unsigned int u = v.u;
    return (unsigned short)((u + 0x7FFFu + ((u >> 16) & 1u)) >> 16); // RNE
}

__global__ void build_K(const float* __restrict__ weight,
                        const float* __restrict__ P,
                        unsigned short* __restrict__ Kws) {
    __shared__ float sacc[128 * 81];           // 41.5 KB
    int tid = threadIdx.x;                     // 128 threads
    int pair = blockIdx.x * 128 + tid;         // o*128 + c
    int o = pair >> 7, c = pair & 127;
    float* a = &sacc[tid * 81];
    for (int i = 0; i < 81; ++i) a[i] = 0.0f;
    int base = pair * 9;
    #pragma unroll
    for (int kh = 0; kh < 3; ++kh) {
        #pragma unroll
        for (int kw = 0; kw < 3; ++kw) {
            int kk = kh * 3 + kw;
            float w  = weight[base + kk];
            float p0 = P[base + kk];
            float p1 = P[128 * 128 * 9 + base + kk];
            float ph = fminf(fmaxf((float)(kh * 4) + p0, 0.0f), 8.0f);
            float pw = fminf(fmaxf((float)(kw * 4) + p1, 0.0f), 8.0f);
            float fh = floorf(ph), fw = floorf(pw);
            float rh = ph - fh, rw = pw - fw;
            int ih = (int)fh, iw = (int)fw;
            int ih1 = min(ih + 1, 8), iw1 = min(iw + 1, 8);
            a[ih  * 9 + iw ] += w * (1.0f - rh) * (1.0f - rw);
            a[ih1 * 9 + iw ] += w * rh * (1.0f - rw);
            a[ih  * 9 + iw1] += w * (1.0f - rh) * rw;
            a[ih1 * 9 + iw1] += w * rh * rw;
        }
    }
    int chunk = c >> 4, half = (c >> 3) & 1, clo = c & 7;
    for (int tap = 0; tap < 81; ++tap) {
        int idx = ((tap * 8 + chunk) * 2 + half) * 1024 + o * 8 + clo;
        Kws[idx] = f2bf(a[tap]);
    }
}

// LDS: x window: 24 rows x 2 c-halves x 24 cols x 16B = 18432 B
//      K group:  9 taps x 2 c-halves x 128 o x 16B   = 36864 B
__global__ __launch_bounds__(256, 2)
void dcls_conv(const float* __restrict__ x,
               const unsigned short* __restrict__ Kws,
               const float* __restrict__ bias,
               float* __restrict__ out) {
    __shared__ __align__(16) char smem[18432 + 36864];
    char* sX = smem;
    char* sK = smem + 18432;

    int bid = blockIdx.x;             // 784 = 16 * 7 * 7
    int b   = bid / 49;
    int rem = bid % 49;
    int ty  = rem / 7, tx = rem % 7;
    int y0  = ty * 16, x0 = tx * 16;

    int tid  = threadIdx.x;
    int lane = tid & 63;
    int wave = tid >> 6;
    int mgrp = wave >> 1;             // 0..1 -> m-tiles {2m, 2m+1}
    int ngrp = wave & 1;              // 0..1 -> n-tiles {4n..4n+3}
    int half = lane >> 5;             // c-half within 16-chunk
    int l31  = lane & 31;
    int lrow = (lane >> 4) & 1;       // row within n-tile
    int lcol = lane & 15;             // col within n-tile

    f32x16 acc[2][4];
    #pragma unroll
    for (int i = 0; i < 2; ++i)
        #pragma unroll
        for (int j = 0; j < 4; ++j)
            #pragma unroll
            for (int k = 0; k < 16; ++k) acc[i][j][k] = 0.0f;

    int preA[2];
    #pragma unroll
    for (int i = 0; i < 2; ++i)
        preA[i] = half * 2048 + ((mgrp * 2 + i) * 32 + l31) * 16;
    int preB[4];
    #pragma unroll
    for (int j = 0; j < 4; ++j)
        preB[j] = (2 * (ngrp * 4 + j) + lrow) * 768 + half * 384 + lcol * 16;

    for (int cc = 0; cc < 8; ++cc) {
        __syncthreads();              // previous iteration's LDS reads done
        // ---- stage x window (fp32 -> bf16), 1152 16B units ----
        {
            int cbase = cc * 16;
            #pragma unroll
            for (int it = 0; it < 5; ++it) {
                int u = tid + it * 256;
                if (u < 1152) {
                    int r  = u / 48;
                    int rr = u % 48;
                    int hf = rr / 24;
                    int co = rr % 24;
                    int h = y0 - 4 + r;
                    int w = x0 - 4 + co;
                    bool ok = (h >= 0) & (h < 112) & (w >= 0) & (w < 112);
                    const float* xp = x + (((b * 128 + cbase + hf * 8) * 112 + h) * 112 + w);
                    short8 v;
                    #pragma unroll
                    for (int j = 0; j < 8; ++j) {
                        float f = ok ? xp[j * 112 * 112] : 0.0f;
                        v[j] = (short)f2bf(f);
                    }
                    *(short8*)(sX + u * 16) = v;
                }
            }
        }
        // ---- 9 tap-groups of 9 taps (group tg == kernel row ih) ----
        for (int tg = 0; tg < 9; ++tg) {
            __syncthreads();          // prev group's sK reads done (covers sX stage too)
            #pragma unroll
            for (int t = 0; t < 9; ++t) {
                int tap = tg * 9 + t;
                const short8* src = (const short8*)(Kws + (tap * 8 + cc) * 2048);
                *(short8*)(sK + t * 4096 + tid * 16) = src[tid];
            }
            __syncthreads();
            #pragma unroll
            for (int t = 0; t < 9; ++t) {   // ih = tg, iw = t
                short8 af[2];
                #pragma unroll
                for (int i = 0; i < 2; ++i)
                    af[i] = *(const short8*)(sK + t * 4096 + preA[i]);
                short8 bfr[4];
                int tapoff = tg * 768 + t * 16;
                #pragma unroll
                for (int j = 0; j < 4; ++j)
                    bfr[j] = *(const short8*)(sX + preB[j] + tapoff);
                #pragma unroll
                for (int i = 0; i < 2; ++i)
                    #pragma unroll
                    for (int j = 0; j < 4; ++j)
                        acc[i][j] = __builtin_amdgcn_mfma_f32_32x32x16_bf16(
                            af[i], bfr[j], acc[i][j], 0, 0, 0);
            }
        }
    }

    // ---- epilogue: C/D layout col=lane&31, row=(r&3)+8*(r>>2)+4*half ----
    #pragma unroll
    for (int i = 0; i < 2; ++i) {
        int ob = (mgrp * 2 + i) * 32;
        #pragma unroll
        for (int r = 0; r < 16; ++r) {
            int o = ob + (r & 3) + 8 * (r >> 2) + 4 * half;
            float bv = bias[o];
            #pragma unroll
            for (int j = 0; j < 4; ++j) {
                int nt  = ngrp * 4 + j;
                int row = y0 + 2 * nt + lrow;
                int col = x0 + lcol;
                out[((b * 128 + o) * 112 + row) * 112 + col] = acc[i][j][r] + bv;
            }
        }
    }
}

extern "C" void kernel_launch(void* const* d_in, const int* in_sizes, int n_in,
                              void* d_out, int out_size, void* d_ws, size_t ws_size,
                              hipStream_t stream) {
    const float* x      = (const float*)d_in[0];
    const float* weight = (const float*)d_in[1];
    const float* P      = (const float*)d_in[2];
    const float* bias   = (const float*)d_in[3];
    float* out = (float*)d_out;
    unsigned short* Kws = (unsigned short*)d_ws;   // 81*128*128 bf16 = 2.65 MB

    build_K<<<128, 128, 0, stream>>>(weight, P, Kws);
    dcls_conv<<<784, 256, 0, stream>>>(x, Kws, bias, out);
}